// Round 1
// baseline (931.356 us; speedup 1.0000x reference)
//
#include <hip/hip_runtime.h>
#include <stdint.h>

#define TB_ 32
#define C_ 256
#define N_ 3136
#define TBC (C_ * N_)            // 802816 elems per (t,b) per 256-ch tensor
#define ACT_SZ (TB_ * TBC)       // 25690112

// ---------------------------------------------------------------------------
// small-int "dot4" on packed bytes (manual — avoids relying on v_dot4 presence)
// ---------------------------------------------------------------------------
__device__ __forceinline__ int dot4u(unsigned a, unsigned b, int c) {
  c += (int)(a & 255u)         * (int)(b & 255u);
  c += (int)((a >> 8) & 255u)  * (int)((b >> 8) & 255u);
  c += (int)((a >> 16) & 255u) * (int)((b >> 16) & 255u);
  c += (int)(a >> 24)          * (int)(b >> 24);
  return c;
}

// ---------------------------------------------------------------------------
// K0: fold BN params: s = gamma/sqrt(var+eps), b = beta - mean*s
// bnw layout: [conv 0..3][ s[256] | b[256] ]
// ---------------------------------------------------------------------------
__global__ void bn_prep(const float* __restrict__ qbn, const float* __restrict__ kbn,
                        const float* __restrict__ vbn, const float* __restrict__ pbn,
                        float* __restrict__ bnw) {
  int c = threadIdx.x;
  const float* ps[4] = {qbn, kbn, vbn, pbn};
#pragma unroll
  for (int i = 0; i < 4; ++i) {
    const float* p = ps[i];
    float g = p[c], be = p[256 + c], mn = p[512 + c], vr = p[768 + c];
    float s = g / sqrtf(vr + 1e-5f);               // IEEE sqrt/div, matches np
    float b = __fsub_rn(be, __fmul_rn(mn, s));     // two roundings, matches np
    bnw[i * 512 + c] = s;
    bnw[i * 512 + 256 + c] = b;
  }
}

// ---------------------------------------------------------------------------
// K1: xs = clip(round(x),0,8) as u8 spikes
// ---------------------------------------------------------------------------
__global__ void quant_x(const float* __restrict__ x, uint8_t* __restrict__ xs, int n4) {
  int i = blockIdx.x * blockDim.x + threadIdx.x;
  int stride = gridDim.x * blockDim.x;
  for (; i < n4; i += stride) {
    float4 v = ((const float4*)x)[i];
    uchar4 o;
    o.x = (uint8_t)fminf(fmaxf(rintf(v.x), 0.f), 8.f);
    o.y = (uint8_t)fminf(fmaxf(rintf(v.y), 0.f), 8.f);
    o.z = (uint8_t)fminf(fmaxf(rintf(v.z), 0.f), 8.f);
    o.w = (uint8_t)fminf(fmaxf(rintf(v.w), 0.f), 8.f);
    ((uchar4*)xs)[i] = o;
  }
}

// ---------------------------------------------------------------------------
// K2: q/k/v = quant(BN(W @ xs/8)) as u8 spikes.
// grid: (25 n-tiles of 128, 6 row-tiles of 128 [2 per conv], 32 tb), 256 thr.
// 128x128 output tile, 8x8 per thread, BK=32, fp32 VALU FMA.
// ---------------------------------------------------------------------------
__global__ __launch_bounds__(256) void qkv_gemm(
    const uint8_t* __restrict__ xs,
    const float* __restrict__ qw, const float* __restrict__ kw,
    const float* __restrict__ vw, const float* __restrict__ bnw,
    uint8_t* __restrict__ qs, uint8_t* __restrict__ ks, uint8_t* __restrict__ vs) {
  __shared__ float sA[32][132];   // [k][row]  (+4 pad keeps b128 16B-aligned)
  __shared__ float sB[32][132];   // [k][col]
  const int tid = threadIdx.x;
  const int tx = tid & 15, ty = tid >> 4;
  const int n0 = blockIdx.x * 128;
  const int rtile = blockIdx.y;
  const int tb = blockIdx.z;
  const int conv = rtile >> 1;
  const int rbase = (rtile & 1) * 128;
  const float* W = conv == 0 ? qw : (conv == 1 ? kw : vw);
  uint8_t* outp = (conv == 0 ? qs : (conv == 1 ? ks : vs)) + tb * TBC;
  const uint8_t* X = xs + tb * TBC;

  float acc[8][8] = {};

  for (int kk = 0; kk < 256; kk += 32) {
    // stage A: 128 rows x 32 k (float4 global, transposed scatter to LDS)
#pragma unroll
    for (int i = 0; i < 4; ++i) {
      int idx = tid + i * 256;            // 1024 float4 slots
      int r = idx >> 3, kq = idx & 7;
      float4 w4 = *(const float4*)&W[(rbase + r) * 256 + kk + kq * 4];
      sA[kq * 4 + 0][r] = w4.x;
      sA[kq * 4 + 1][r] = w4.y;
      sA[kq * 4 + 2][r] = w4.z;
      sA[kq * 4 + 3][r] = w4.w;
    }
    // stage B: 32 k x 128 n from u8 (u32 loads, unpack to float)
#pragma unroll
    for (int i = 0; i < 4; ++i) {
      int idx = tid + i * 256;            // 1024 u32 slots
      int k = idx >> 5, c4 = idx & 31;
      int n = n0 + c4 * 4;
      unsigned wrd = 0;
      if (n < N_) wrd = *(const unsigned*)&X[(kk + k) * N_ + n];
      sB[k][c4 * 4 + 0] = (float)(wrd & 255u);
      sB[k][c4 * 4 + 1] = (float)((wrd >> 8) & 255u);
      sB[k][c4 * 4 + 2] = (float)((wrd >> 16) & 255u);
      sB[k][c4 * 4 + 3] = (float)(wrd >> 24);
    }
    __syncthreads();
#pragma unroll 8
    for (int k = 0; k < 32; ++k) {
      float4 a0 = *(const float4*)&sA[k][ty * 8];
      float4 a1 = *(const float4*)&sA[k][ty * 8 + 4];
      float4 b0 = *(const float4*)&sB[k][tx * 8];
      float4 b1 = *(const float4*)&sB[k][tx * 8 + 4];
      float av[8] = {a0.x, a0.y, a0.z, a0.w, a1.x, a1.y, a1.z, a1.w};
      float bv[8] = {b0.x, b0.y, b0.z, b0.w, b1.x, b1.y, b1.z, b1.w};
#pragma unroll
      for (int ii = 0; ii < 8; ++ii)
#pragma unroll
        for (int jj = 0; jj < 8; ++jj)
          acc[ii][jj] = fmaf(av[ii], bv[jj], acc[ii][jj]);
    }
    __syncthreads();
  }

  const float* sbn = bnw + conv * 512;
#pragma unroll
  for (int ii = 0; ii < 8; ++ii) {
    int ch = rbase + ty * 8 + ii;
    float s = sbn[ch], b = sbn[256 + ch];
    uint8_t bytes[8];
#pragma unroll
    for (int jj = 0; jj < 8; ++jj) {
      float y = acc[ii][jj] * 0.125f;              // exact pow2 scale (== sum of w*(n/8))
      float t = __fmul_rn(y, s);                   // BN: two distinct roundings (no fma)
      t = __fadd_rn(t, b);
      float r = fminf(fmaxf(rintf(t), 0.f), 8.f);  // quant_if forward
      bytes[jj] = (uint8_t)r;
    }
    int n = n0 + tx * 8;
    if (n < N_)
      *(uchar4*)&outp[ch * N_ + n] = make_uchar4(bytes[0], bytes[1], bytes[2], bytes[3]);
    if (n + 4 < N_)
      *(uchar4*)&outp[ch * N_ + n + 4] = make_uchar4(bytes[4], bytes[5], bytes[6], bytes[7]);
  }
}

// ---------------------------------------------------------------------------
// K3: per (h, tb): kv_int = k_int^T v_int (exact int32), then
// o = quant( (q_int . kv_int) * (2/sqrt(32))/512 ).  grid (8,32), 256 thr.
// ---------------------------------------------------------------------------
__global__ __launch_bounds__(256) void attn_kernel(
    const uint8_t* __restrict__ qs, const uint8_t* __restrict__ ks,
    const uint8_t* __restrict__ vs, uint8_t* __restrict__ os_) {
  const int h = blockIdx.x;
  const int tb = blockIdx.y;
  const int tid = threadIdx.x;
  __shared__ unsigned sk[32][64];   // [d][n-word] 4 n per word
  __shared__ unsigned sv[32][64];
  __shared__ uint8_t sq[256][48];   // transposed q tile [n][d], pad 48 for b128
  __shared__ int kvs[32][33];

  const uint8_t* Q = qs + tb * TBC + h * 32 * N_;
  const uint8_t* K = ks + tb * TBC + h * 32 * N_;
  const uint8_t* V = vs + tb * TBC + h * 32 * N_;
  uint8_t* O = os_ + tb * TBC + h * 32 * N_;

  // ---- phase 1: kv[d][e] over all n (thread owns 2x2 (d,e) pairs) ----
  const int d0 = (tid >> 4) * 2;
  const int e0 = (tid & 15) * 2;
  int acc[2][2] = {};

  for (int nt = 0; nt < 13; ++nt) {
    int n0 = nt * 256;
    __syncthreads();
#pragma unroll
    for (int i = 0; i < 8; ++i) {
      int idx = tid + i * 256;           // 2048 words
      int d = idx >> 6, w = idx & 63;
      int n = n0 + w * 4;
      unsigned kw_ = 0, vw_ = 0;
      if (n < N_) {
        kw_ = *(const unsigned*)&K[d * N_ + n];
        vw_ = *(const unsigned*)&V[d * N_ + n];
      }
      sk[d][w] = kw_;
      sv[d][w] = vw_;
    }
    __syncthreads();
#pragma unroll
    for (int w = 0; w < 64; w += 4) {
      uint4 ka = *(const uint4*)&sk[d0][w];
      uint4 kb = *(const uint4*)&sk[d0 + 1][w];
      uint4 va = *(const uint4*)&sv[e0][w];
      uint4 vb = *(const uint4*)&sv[e0 + 1][w];
      unsigned kwds[2][4] = {{ka.x, ka.y, ka.z, ka.w}, {kb.x, kb.y, kb.z, kb.w}};
      unsigned vwds[2][4] = {{va.x, va.y, va.z, va.w}, {vb.x, vb.y, vb.z, vb.w}};
#pragma unroll
      for (int di = 0; di < 2; ++di)
#pragma unroll
        for (int ej = 0; ej < 2; ++ej)
#pragma unroll
          for (int c = 0; c < 4; ++c)
            acc[di][ej] = dot4u(kwds[di][c], vwds[ej][c], acc[di][ej]);
    }
  }
  kvs[d0][e0] = acc[0][0];
  kvs[d0][e0 + 1] = acc[0][1];
  kvs[d0 + 1][e0] = acc[1][0];
  kvs[d0 + 1][e0 + 1] = acc[1][1];
  __syncthreads();

  // ---- phase 2: o[n][e] = sum_d q[d][n]*kv[d][e], scale, quantize ----
  const int e = tid & 31;
  const int g = tid >> 5;
  int kvcol[32];
#pragma unroll
  for (int d = 0; d < 32; ++d) kvcol[d] = kvs[d][e];

  // (2/sqrt(32)) / 512, rounded once to fp32 — exact pow2 shift of np's scale
  const float cscale = (float)(0.3535533905932738 / 512.0);

  for (int nt = 0; nt < 13; ++nt) {
    int n0 = nt * 256;
    __syncthreads();
#pragma unroll
    for (int i = 0; i < 8; ++i) {
      int idx = tid + i * 256;
      int d = idx >> 6, w = idx & 63;
      int n = n0 + w * 4;
      unsigned qw_ = 0;
      if (n < N_) qw_ = *(const unsigned*)&Q[d * N_ + n];
      sq[w * 4 + 0][d] = (uint8_t)(qw_ & 255u);
      sq[w * 4 + 1][d] = (uint8_t)((qw_ >> 8) & 255u);
      sq[w * 4 + 2][d] = (uint8_t)((qw_ >> 16) & 255u);
      sq[w * 4 + 3][d] = (uint8_t)(qw_ >> 24);
    }
    __syncthreads();
#pragma unroll
    for (int s8 = 0; s8 < 8; ++s8) {
      int nl = (s8 * 8 + g) * 4;         // local quad base, covers 0..255
      int n = n0 + nl;
      uint8_t ob[4];
#pragma unroll
      for (int jn = 0; jn < 4; ++jn) {
        const uint8_t* qrow = &sq[nl + jn][0];
        uint4 qa = *(const uint4*)&qrow[0];
        uint4 qb = *(const uint4*)&qrow[16];
        unsigned qq[8] = {qa.x, qa.y, qa.z, qa.w, qb.x, qb.y, qb.z, qb.w};
        int o = 0;
#pragma unroll
        for (int qi = 0; qi < 8; ++qi)
#pragma unroll
          for (int m = 0; m < 4; ++m)
            o += (int)((qq[qi] >> (8 * m)) & 255u) * kvcol[qi * 4 + m];
        float of = (float)o * cscale;    // single rounding, matches np exactly
        float r = fminf(fmaxf(rintf(of), 0.f), 8.f);
        ob[jn] = (uint8_t)r;
      }
      if (n < N_)
        *(uchar4*)&O[e * N_ + n] = make_uchar4(ob[0], ob[1], ob[2], ob[3]);
    }
  }
}

// ---------------------------------------------------------------------------
// K4: out = BN(pw @ os/8), fp32 output. Same tiling as K2, rows=256.
// ---------------------------------------------------------------------------
__global__ __launch_bounds__(256) void out_gemm(
    const uint8_t* __restrict__ os_, const float* __restrict__ pw,
    const float* __restrict__ bnw, float* __restrict__ out) {
  __shared__ float sA[32][132];
  __shared__ float sB[32][132];
  const int tid = threadIdx.x;
  const int tx = tid & 15, ty = tid >> 4;
  const int n0 = blockIdx.x * 128;
  const int rbase = blockIdx.y * 128;
  const int tb = blockIdx.z;
  const uint8_t* X = os_ + tb * TBC;
  float* O = out + tb * TBC;

  float acc[8][8] = {};

  for (int kk = 0; kk < 256; kk += 32) {
#pragma unroll
    for (int i = 0; i < 4; ++i) {
      int idx = tid + i * 256;
      int r = idx >> 3, kq = idx & 7;
      float4 w4 = *(const float4*)&pw[(rbase + r) * 256 + kk + kq * 4];
      sA[kq * 4 + 0][r] = w4.x;
      sA[kq * 4 + 1][r] = w4.y;
      sA[kq * 4 + 2][r] = w4.z;
      sA[kq * 4 + 3][r] = w4.w;
    }
#pragma unroll
    for (int i = 0; i < 4; ++i) {
      int idx = tid + i * 256;
      int k = idx >> 5, c4 = idx & 31;
      int n = n0 + c4 * 4;
      unsigned wrd = 0;
      if (n < N_) wrd = *(const unsigned*)&X[(kk + k) * N_ + n];
      sB[k][c4 * 4 + 0] = (float)(wrd & 255u);
      sB[k][c4 * 4 + 1] = (float)((wrd >> 8) & 255u);
      sB[k][c4 * 4 + 2] = (float)((wrd >> 16) & 255u);
      sB[k][c4 * 4 + 3] = (float)(wrd >> 24);
    }
    __syncthreads();
#pragma unroll 8
    for (int k = 0; k < 32; ++k) {
      float4 a0 = *(const float4*)&sA[k][ty * 8];
      float4 a1 = *(const float4*)&sA[k][ty * 8 + 4];
      float4 b0 = *(const float4*)&sB[k][tx * 8];
      float4 b1 = *(const float4*)&sB[k][tx * 8 + 4];
      float av[8] = {a0.x, a0.y, a0.z, a0.w, a1.x, a1.y, a1.z, a1.w};
      float bv[8] = {b0.x, b0.y, b0.z, b0.w, b1.x, b1.y, b1.z, b1.w};
#pragma unroll
      for (int ii = 0; ii < 8; ++ii)
#pragma unroll
        for (int jj = 0; jj < 8; ++jj)
          acc[ii][jj] = fmaf(av[ii], bv[jj], acc[ii][jj]);
    }
    __syncthreads();
  }

  const float* sbn = bnw + 3 * 512;
#pragma unroll
  for (int ii = 0; ii < 8; ++ii) {
    int ch = rbase + ty * 8 + ii;
    float s = sbn[ch], b = sbn[256 + ch];
    float v[8];
#pragma unroll
    for (int jj = 0; jj < 8; ++jj) {
      float y = acc[ii][jj] * 0.125f;
      float t = __fmul_rn(y, s);
      v[jj] = __fadd_rn(t, b);
    }
    int n = n0 + tx * 8;
    if (n < N_)
      *(float4*)&O[ch * N_ + n] = make_float4(v[0], v[1], v[2], v[3]);
    if (n + 4 < N_)
      *(float4*)&O[ch * N_ + n + 4] = make_float4(v[4], v[5], v[6], v[7]);
  }
}

// ---------------------------------------------------------------------------
extern "C" void kernel_launch(void* const* d_in, const int* in_sizes, int n_in,
                              void* d_out, int out_size, void* d_ws, size_t ws_size,
                              hipStream_t stream) {
  const float* x   = (const float*)d_in[0];
  const float* qw  = (const float*)d_in[1];
  const float* qbn = (const float*)d_in[2];
  const float* kw  = (const float*)d_in[3];
  const float* kbn = (const float*)d_in[4];
  const float* vw  = (const float*)d_in[5];
  const float* vbn = (const float*)d_in[6];
  const float* pw  = (const float*)d_in[7];
  const float* pbn = (const float*)d_in[8];
  float* out = (float*)d_out;

  uint8_t* ws = (uint8_t*)d_ws;
  float* bnw   = (float*)ws;            // 8 KB
  uint8_t* xs  = ws + 8192;
  uint8_t* qsp = xs + ACT_SZ;
  uint8_t* ksp = qsp + ACT_SZ;
  uint8_t* vsp = ksp + ACT_SZ;
  uint8_t* osp = vsp + ACT_SZ;          // total ~128.5 MB of d_ws

  bn_prep<<<1, 256, 0, stream>>>(qbn, kbn, vbn, pbn, bnw);
  quant_x<<<2048, 256, 0, stream>>>(x, xs, ACT_SZ / 4);
  qkv_gemm<<<dim3(25, 6, 32), 256, 0, stream>>>(xs, qw, kw, vw, bnw, qsp, ksp, vsp);
  attn_kernel<<<dim3(8, 32), 256, 0, stream>>>(qsp, ksp, vsp, osp);
  out_gemm<<<dim3(25, 2, 32), 256, 0, stream>>>(osp, pw, bnw, out);
}

// Round 2
// 714.841 us; speedup vs baseline: 1.3029x; 1.3029x over previous
//
#include <hip/hip_runtime.h>
#include <stdint.h>

#define TB_ 32
#define C_ 256
#define N_ 3136
#define TBC (C_ * N_)            // 802816 elems per (t,b) per 256-ch tensor
#define ACT_SZ (TB_ * TBC)       // 25690112
#define XSB_TB 819200            // u16 elems per tb in blocked xs (200 groups * 4096)

typedef __attribute__((ext_vector_type(8))) short bf16x8;
typedef __attribute__((ext_vector_type(4))) float f32x4;

__device__ __forceinline__ void glds16(const void* gp, void* lp) {
  __builtin_amdgcn_global_load_lds(
      (const __attribute__((address_space(1))) unsigned int*)gp,
      (__attribute__((address_space(3))) unsigned int*)lp, 16, 0, 0);
}

__device__ __forceinline__ unsigned short bf16rn(float f, float* val) {
  unsigned b = __float_as_uint(f);
  unsigned r = (b + 0x7fffu + ((b >> 16) & 1u)) >> 16;
  *val = __uint_as_float(r << 16);
  return (unsigned short)r;
}

// small-int "dot4" on packed bytes
__device__ __forceinline__ int dot4u(unsigned a, unsigned b, int c) {
  c += (int)(a & 255u)         * (int)(b & 255u);
  c += (int)((a >> 8) & 255u)  * (int)((b >> 8) & 255u);
  c += (int)((a >> 16) & 255u) * (int)((b >> 16) & 255u);
  c += (int)(a >> 24)          * (int)(b >> 24);
  return c;
}

// ---------------------------------------------------------------------------
// K0: fold BN params: s = gamma/sqrt(var+eps), b = beta - mean*s
// ---------------------------------------------------------------------------
__global__ void bn_prep(const float* __restrict__ qbn, const float* __restrict__ kbn,
                        const float* __restrict__ vbn, const float* __restrict__ pbn,
                        float* __restrict__ bnw) {
  int c = threadIdx.x;
  const float* ps[4] = {qbn, kbn, vbn, pbn};
#pragma unroll
  for (int i = 0; i < 4; ++i) {
    const float* p = ps[i];
    float g = p[c], be = p[256 + c], mn = p[512 + c], vr = p[768 + c];
    float s = g / sqrtf(vr + 1e-5f);
    float b = __fsub_rn(be, __fmul_rn(mn, s));
    bnw[i * 512 + c] = s;
    bnw[i * 512 + 256 + c] = b;
  }
}

// ---------------------------------------------------------------------------
// K0b: split fp32 weights into 3 exact bf16 terms, laid out in MFMA
// A-fragment image order so the GEMM can stage with linear global_load_lds.
// layout (u16): [m(4)][split(3)][rt(2)][kstep(8)] -> 4096 elems = 8KB image,
// image = [mtile(8)][lane(64)][j(8)], lane = (co&15) + 16*((k>>3)&3).
// ---------------------------------------------------------------------------
__global__ void wprep(const float* __restrict__ qw, const float* __restrict__ kw,
                      const float* __restrict__ vw, const float* __restrict__ pw,
                      unsigned short* __restrict__ wsp) {
  const float* Ws[4] = {qw, kw, vw, pw};
  int m = blockIdx.y, co = blockIdx.x, k = threadIdx.x;
  float w = Ws[m][co * 256 + k];
  float h1, h2, h3r;
  unsigned short u1 = bf16rn(w, &h1);
  float r1 = __fsub_rn(w, h1);             // exact (Sterbenz)
  unsigned short u2 = bf16rn(r1, &h2);
  float r2 = __fsub_rn(r1, h2);            // exact, <=8 significant bits
  unsigned short u3 = bf16rn(r2, &h3r);
  int rt = co >> 7, mt = (co >> 4) & 7, ks = k >> 5;
  int lane = (co & 15) + 16 * ((k >> 3) & 3);
  unsigned short us[3] = {u1, u2, u3};
#pragma unroll
  for (int sp = 0; sp < 3; ++sp) {
    size_t off = (size_t)((((m * 3 + sp) * 2 + rt) * 8 + ks)) * 4096 + lane * 8 + (k & 7);
    wsp[off] = us[sp];
  }
}

// ---------------------------------------------------------------------------
// K1: x -> spikes (bf16 exact values 0..8) in blocked B-fragment layout:
// xsb[tb][g=n>>4][cc=c>>3][n&15][c&7]  (u16).  Conflict-free 2-stage LDS.
// ---------------------------------------------------------------------------
__global__ __launch_bounds__(256) void quant_x_t(const float* __restrict__ x,
                                                 unsigned short* __restrict__ xsb) {
  __shared__ unsigned short s[64 * 65];   // [c][n] padded
  const int t = threadIdx.x;
  const int bx = blockIdx.x;              // 49 tiles of 64 pixels
  const int tb = blockIdx.y;
  const int n0 = bx * 64;
  const float* X = x + (size_t)tb * TBC;
  const int nl = t & 63, cq = t >> 6;

  unsigned short* dstb = xsb + (size_t)tb * XSB_TB;
  // process channels in chunks of 64 (LDS holds 64c x 64n)
  for (int cb = 0; cb < 4; ++cb) {
    int cbase = cb * 64;
#pragma unroll 4
    for (int i = 0; i < 16; ++i) {
      int c = i * 4 + cq;                 // 0..63 local
      float v = X[(size_t)(cbase + c) * N_ + n0 + nl];
      float r = fminf(fmaxf(rintf(v), 0.f), 8.f);
      s[c * 65 + nl] = (unsigned short)(__float_as_uint(r) >> 16);
    }
    __syncthreads();
    // each thread packs 8 channels of one pixel -> one 16B chunk
#pragma unroll 2
    for (int j = 0; j < 2; ++j) {
      int ccl = j * 4 + cq;               // local c-chunk 0..7
      int cc = cb * 8 + ccl;              // global c-chunk 0..31
      unsigned short v8[8];
#pragma unroll
      for (int d = 0; d < 8; ++d) v8[d] = s[(ccl * 8 + d) * 65 + nl];
      int n = n0 + nl;
      uint4 pk;
      pk.x = (unsigned)v8[0] | ((unsigned)v8[1] << 16);
      pk.y = (unsigned)v8[2] | ((unsigned)v8[3] << 16);
      pk.z = (unsigned)v8[4] | ((unsigned)v8[5] << 16);
      pk.w = (unsigned)v8[6] | ((unsigned)v8[7] << 16);
      *(uint4*)&dstb[(size_t)(n >> 4) * 4096 + cc * 128 + (n & 15) * 8] = pk;
    }
    __syncthreads();
  }
}

// ---------------------------------------------------------------------------
// K2: q/k/v = quant(BN(W @ s/8)) via bf16 MFMA, 3-term split weights.
// grid (25 ntile, 32 tb, 6 [conv*2+rt]), 256 thr = 4 waves, 128x128 tile.
// ---------------------------------------------------------------------------
__global__ __launch_bounds__(256) void qkv_mfma(
    const unsigned short* __restrict__ xsb, const unsigned short* __restrict__ wsp,
    const float* __restrict__ bnw,
    uint8_t* __restrict__ qs, uint8_t* __restrict__ ks_, uint8_t* __restrict__ vs) {
  __shared__ __align__(16) char smem[16384];
  char* smA = smem;
  char* smB = smem + 8192;
  const int t = threadIdx.x;
  const int L = t & 63, w = t >> 6;
  const int wrow = w >> 1, wcol = w & 1;
  const int n0 = blockIdx.x * 128;
  const int tb = blockIdx.y;
  const int conv = blockIdx.z >> 1, rt = blockIdx.z & 1;

  const char* Bb = (const char*)(xsb + (size_t)tb * XSB_TB) + (size_t)blockIdx.x * 65536;

  f32x4 acc[4][4];
#pragma unroll
  for (int i = 0; i < 4; ++i)
#pragma unroll
    for (int j = 0; j < 4; ++j) acc[i][j] = (f32x4){0.f, 0.f, 0.f, 0.f};

  for (int sp = 0; sp < 3; ++sp) {
    const char* Asp = (const char*)wsp + ((size_t)(conv * 3 + sp) * 16 + rt * 8) * 8192;
#pragma unroll 1
    for (int ks2 = 0; ks2 < 8; ++ks2) {
      __syncthreads();
      const char* Ak = Asp + ks2 * 8192;
      glds16(Ak + t * 16, smA + t * 16);
      glds16(Ak + t * 16 + 4096, smA + t * 16 + 4096);
      const char* Bk = Bb + ks2 * 1024;
      glds16(Bk + (size_t)w * 8192 + L * 16, smB + t * 16);
      glds16(Bk + (size_t)(w + 4) * 8192 + L * 16, smB + t * 16 + 4096);
      __syncthreads();
      bf16x8 af[4], bfr[4];
#pragma unroll
      for (int i = 0; i < 4; ++i) {
        af[i] = *(const bf16x8*)(smA + (wrow * 4 + i) * 1024 + L * 16);
        bfr[i] = *(const bf16x8*)(smB + (wcol * 4 + i) * 1024 + L * 16);
      }
#pragma unroll
      for (int i = 0; i < 4; ++i)
#pragma unroll
        for (int j = 0; j < 4; ++j)
          acc[i][j] = __builtin_amdgcn_mfma_f32_16x16x32_bf16(af[i], bfr[j], acc[i][j], 0, 0, 0);
    }
  }

  uint8_t* outp = (conv == 0 ? qs : (conv == 1 ? ks_ : vs)) + (size_t)tb * TBC;
  const float* sbn = bnw + conv * 512;
  const int rbase = rt * 128;
#pragma unroll
  for (int i = 0; i < 4; ++i) {
    int co0 = rbase + wrow * 64 + i * 16 + ((L >> 4) << 2);
#pragma unroll
    for (int j = 0; j < 4; ++j) {
      int n = n0 + wcol * 64 + j * 16 + (L & 15);
      if (n < N_) {
#pragma unroll
        for (int r = 0; r < 4; ++r) {
          int co = co0 + r;
          float y = acc[i][j][r] * 0.125f;
          float tt = __fadd_rn(__fmul_rn(y, sbn[co]), sbn[256 + co]);
          float rr = fminf(fmaxf(rintf(tt), 0.f), 8.f);
          outp[(size_t)co * N_ + n] = (uint8_t)rr;
        }
      }
    }
  }
}

// ---------------------------------------------------------------------------
// K3: attention (unchanged from round 1 — exact int32 path)
// ---------------------------------------------------------------------------
__global__ __launch_bounds__(256) void attn_kernel(
    const uint8_t* __restrict__ qs, const uint8_t* __restrict__ ks,
    const uint8_t* __restrict__ vs, uint8_t* __restrict__ os_) {
  const int h = blockIdx.x;
  const int tb = blockIdx.y;
  const int tid = threadIdx.x;
  __shared__ unsigned sk[32][64];
  __shared__ unsigned sv[32][64];
  __shared__ uint8_t sq[256][48];
  __shared__ int kvs[32][33];

  const uint8_t* Q = qs + tb * TBC + h * 32 * N_;
  const uint8_t* K = ks + tb * TBC + h * 32 * N_;
  const uint8_t* V = vs + tb * TBC + h * 32 * N_;
  uint8_t* O = os_ + tb * TBC + h * 32 * N_;

  const int d0 = (tid >> 4) * 2;
  const int e0 = (tid & 15) * 2;
  int acc[2][2] = {};

  for (int nt = 0; nt < 13; ++nt) {
    int n0 = nt * 256;
    __syncthreads();
#pragma unroll
    for (int i = 0; i < 8; ++i) {
      int idx = tid + i * 256;
      int d = idx >> 6, w = idx & 63;
      int n = n0 + w * 4;
      unsigned kw_ = 0, vw_ = 0;
      if (n < N_) {
        kw_ = *(const unsigned*)&K[d * N_ + n];
        vw_ = *(const unsigned*)&V[d * N_ + n];
      }
      sk[d][w] = kw_;
      sv[d][w] = vw_;
    }
    __syncthreads();
#pragma unroll
    for (int w = 0; w < 64; w += 4) {
      uint4 ka = *(const uint4*)&sk[d0][w];
      uint4 kb = *(const uint4*)&sk[d0 + 1][w];
      uint4 va = *(const uint4*)&sv[e0][w];
      uint4 vb = *(const uint4*)&sv[e0 + 1][w];
      unsigned kwds[2][4] = {{ka.x, ka.y, ka.z, ka.w}, {kb.x, kb.y, kb.z, kb.w}};
      unsigned vwds[2][4] = {{va.x, va.y, va.z, va.w}, {vb.x, vb.y, vb.z, vb.w}};
#pragma unroll
      for (int di = 0; di < 2; ++di)
#pragma unroll
        for (int ej = 0; ej < 2; ++ej)
#pragma unroll
          for (int c = 0; c < 4; ++c)
            acc[di][ej] = dot4u(kwds[di][c], vwds[ej][c], acc[di][ej]);
    }
  }
  kvs[d0][e0] = acc[0][0];
  kvs[d0][e0 + 1] = acc[0][1];
  kvs[d0 + 1][e0] = acc[1][0];
  kvs[d0 + 1][e0 + 1] = acc[1][1];
  __syncthreads();

  const int e = tid & 31;
  const int g = tid >> 5;
  int kvcol[32];
#pragma unroll
  for (int d = 0; d < 32; ++d) kvcol[d] = kvs[d][e];

  const float cscale = (float)(0.3535533905932738 / 512.0);

  for (int nt = 0; nt < 13; ++nt) {
    int n0 = nt * 256;
    __syncthreads();
#pragma unroll
    for (int i = 0; i < 8; ++i) {
      int idx = tid + i * 256;
      int d = idx >> 6, w = idx & 63;
      int n = n0 + w * 4;
      unsigned qw_ = 0;
      if (n < N_) qw_ = *(const unsigned*)&Q[d * N_ + n];
      sq[w * 4 + 0][d] = (uint8_t)(qw_ & 255u);
      sq[w * 4 + 1][d] = (uint8_t)((qw_ >> 8) & 255u);
      sq[w * 4 + 2][d] = (uint8_t)((qw_ >> 16) & 255u);
      sq[w * 4 + 3][d] = (uint8_t)(qw_ >> 24);
    }
    __syncthreads();
#pragma unroll
    for (int s8 = 0; s8 < 8; ++s8) {
      int nl = (s8 * 8 + g) * 4;
      int n = n0 + nl;
      uint8_t ob[4];
#pragma unroll
      for (int jn = 0; jn < 4; ++jn) {
        const uint8_t* qrow = &sq[nl + jn][0];
        uint4 qa = *(const uint4*)&qrow[0];
        uint4 qb = *(const uint4*)&qrow[16];
        unsigned qq[8] = {qa.x, qa.y, qa.z, qa.w, qb.x, qb.y, qb.z, qb.w};
        int o = 0;
#pragma unroll
        for (int qi = 0; qi < 8; ++qi)
#pragma unroll
          for (int m = 0; m < 4; ++m)
            o += (int)((qq[qi] >> (8 * m)) & 255u) * kvcol[qi * 4 + m];
        float of = (float)o * cscale;
        float r = fminf(fmaxf(rintf(of), 0.f), 8.f);
        ob[jn] = (uint8_t)r;
      }
      if (n < N_)
        *(uchar4*)&O[e * N_ + n] = make_uchar4(ob[0], ob[1], ob[2], ob[3]);
    }
  }
}

// ---------------------------------------------------------------------------
// K4: out = BN(pw @ os/8) via bf16 MFMA; B staged from u8 with VALU unpack
// into fragment-image LDS (bank-rotated b16 writes).
// grid (25, 32, 2[rt]).
// ---------------------------------------------------------------------------
__global__ __launch_bounds__(256) void out_mfma(
    const uint8_t* __restrict__ os_, const unsigned short* __restrict__ wsp,
    const float* __restrict__ bnw, float* __restrict__ out) {
  __shared__ __align__(16) char smem[16384];
  char* smA = smem;
  char* smB = smem + 8192;
  const int t = threadIdx.x;
  const int L = t & 63, w = t >> 6;
  const int wrow = w >> 1, wcol = w & 1;
  const int n0 = blockIdx.x * 128;
  const int tb = blockIdx.y;
  const int rt = blockIdx.z;
  const uint8_t* X = os_ + (size_t)tb * TBC;

  f32x4 acc[4][4];
#pragma unroll
  for (int i = 0; i < 4; ++i)
#pragma unroll
    for (int j = 0; j < 4; ++j) acc[i][j] = (f32x4){0.f, 0.f, 0.f, 0.f};

  for (int sp = 0; sp < 3; ++sp) {
    const char* Asp = (const char*)wsp + ((size_t)(9 + sp) * 16 + rt * 8) * 8192;  // matrix 3 = pw
#pragma unroll 1
    for (int ks2 = 0; ks2 < 8; ++ks2) {
      __syncthreads();
      const char* Ak = Asp + ks2 * 8192;
      glds16(Ak + t * 16, smA + t * 16);
      glds16(Ak + t * 16 + 4096, smA + t * 16 + 4096);
      // B: unpack 32c x 128n u8 -> bf16 frag image
#pragma unroll
      for (int i2 = 0; i2 < 4; ++i2) {
        int id = t + 256 * i2;
        int cl = id >> 5, nq = id & 31;
        int n = n0 + nq * 4;
        unsigned wv = 0;
        if (n < N_) wv = *(const unsigned*)&X[(size_t)(ks2 * 32 + cl) * N_ + n];
        int ntile = nq >> 2, cc = cl >> 3, jj = cl & 7;
        unsigned short* dsts = (unsigned short*)(smB + ntile * 1024 + cc * 256 + jj * 2);
#pragma unroll
        for (int dd = 0; dd < 4; ++dd) {
          int d = ((nq >> 2) + dd) & 3;   // bank-rotated order
          float f = (float)((wv >> (8 * d)) & 255u);
          dsts[((nq & 3) * 4 + d) * 8] = (unsigned short)(__float_as_uint(f) >> 16);
        }
      }
      __syncthreads();
      bf16x8 af[4], bfr[4];
#pragma unroll
      for (int i = 0; i < 4; ++i) {
        af[i] = *(const bf16x8*)(smA + (wrow * 4 + i) * 1024 + L * 16);
        bfr[i] = *(const bf16x8*)(smB + (wcol * 4 + i) * 1024 + L * 16);
      }
#pragma unroll
      for (int i = 0; i < 4; ++i)
#pragma unroll
        for (int j = 0; j < 4; ++j)
          acc[i][j] = __builtin_amdgcn_mfma_f32_16x16x32_bf16(af[i], bfr[j], acc[i][j], 0, 0, 0);
    }
  }

  float* O = out + (size_t)tb * TBC;
  const float* sbn = bnw + 3 * 512;
  const int rbase = rt * 128;
#pragma unroll
  for (int i = 0; i < 4; ++i) {
    int co0 = rbase + wrow * 64 + i * 16 + ((L >> 4) << 2);
#pragma unroll
    for (int j = 0; j < 4; ++j) {
      int n = n0 + wcol * 64 + j * 16 + (L & 15);
      if (n < N_) {
#pragma unroll
        for (int r = 0; r < 4; ++r) {
          int co = co0 + r;
          float y = acc[i][j][r] * 0.125f;
          O[(size_t)co * N_ + n] = __fadd_rn(__fmul_rn(y, sbn[co]), sbn[256 + co]);
        }
      }
    }
  }
}

// ---------------------------------------------------------------------------
extern "C" void kernel_launch(void* const* d_in, const int* in_sizes, int n_in,
                              void* d_out, int out_size, void* d_ws, size_t ws_size,
                              hipStream_t stream) {
  const float* x   = (const float*)d_in[0];
  const float* qw  = (const float*)d_in[1];
  const float* qbn = (const float*)d_in[2];
  const float* kw  = (const float*)d_in[3];
  const float* kbn = (const float*)d_in[4];
  const float* vw  = (const float*)d_in[5];
  const float* vbn = (const float*)d_in[6];
  const float* pw  = (const float*)d_in[7];
  const float* pbn = (const float*)d_in[8];
  float* out = (float*)d_out;

  uint8_t* ws = (uint8_t*)d_ws;
  float* bnw           = (float*)ws;                         // 8 KB
  unsigned short* wsp  = (unsigned short*)(ws + 8192);       // 1.5 MB (4 mat x 3 split)
  unsigned short* xsb  = (unsigned short*)(ws + 1581056);    // 52.4 MB blocked spikes
  uint8_t* qsp = ws + 54009856;
  uint8_t* ksp = qsp + ACT_SZ;
  uint8_t* vsp = ksp + ACT_SZ;
  uint8_t* osp = (uint8_t*)xsb;   // alias: xsb dead after qkv_mfma, os written by attn

  bn_prep<<<1, 256, 0, stream>>>(qbn, kbn, vbn, pbn, bnw);
  wprep<<<dim3(256, 4), 256, 0, stream>>>(qw, kw, vw, pw, wsp);
  quant_x_t<<<dim3(49, 32), 256, 0, stream>>>(x, xsb);
  qkv_mfma<<<dim3(25, 32, 6), 256, 0, stream>>>(xsb, wsp, bnw, qsp, ksp, vsp);
  attn_kernel<<<dim3(8, 32), 256, 0, stream>>>(qsp, ksp, vsp, osp);
  out_mfma<<<dim3(25, 32, 2), 256, 0, stream>>>(osp, wsp, bnw, out);
}